// Round 2
// baseline (685.886 us; speedup 1.0000x reference)
//
#include <hip/hip_runtime.h>
#include <math.h>

// Problem constants (fixed shapes from reference)
#define E_      256
#define C_      128
#define S_      3136   // 56*56
#define NC_     200
#define NP_     512
#define NL_     64
#define LL_     8
#define EDGE_DIM_ 256  // 2*C
#define LOOP_IN_  258  // EDGE_DIM + 2
#define FEAT_   64

// ---------------------------------------------------------------------------
// K1: global max-pool over H*W per (e,c) row. One 64-lane wave per row.
// Row = 3136 f32 = 784 x float4 chunks = 12 full wave iterations + 16 tail.
// ---------------------------------------------------------------------------
__global__ __launch_bounds__(256) void pool_kernel(const float* __restrict__ image_x,
                                                   float* __restrict__ edge_x) {
    int row  = blockIdx.x * 4 + (threadIdx.x >> 6);   // (e*C + c)
    int lane = threadIdx.x & 63;
    const float4* p = reinterpret_cast<const float4*>(image_x) + (size_t)row * (S_ / 4);

    float m = -INFINITY;
    #pragma unroll
    for (int it = 0; it < 12; ++it) {
        float4 v = p[lane + it * 64];
        m = fmaxf(m, fmaxf(fmaxf(v.x, v.y), fmaxf(v.z, v.w)));
    }
    if (lane < 16) {   // tail chunks 768..783
        float4 v = p[768 + lane];
        m = fmaxf(m, fmaxf(fmaxf(v.x, v.y), fmaxf(v.z, v.w)));
    }
    #pragma unroll
    for (int off = 32; off; off >>= 1) m = fmaxf(m, __shfl_down(m, off));
    if (lane == 0) {
        int e = row >> 7, c = row & 127;
        edge_x[e * EDGE_DIM_ + c] = m;
    }
}

// ---------------------------------------------------------------------------
// K2: copy coord_x into second half of edge_x rows
// ---------------------------------------------------------------------------
__global__ void coord_copy_kernel(const float* __restrict__ coord_x,
                                  float* __restrict__ edge_x) {
    int i = blockIdx.x * 256 + threadIdx.x;   // < E*C
    int e = i >> 7, c = i & 127;
    edge_x[e * EDGE_DIM_ + C_ + c] = coord_x[i];
}

// ---------------------------------------------------------------------------
// K3: edge confidence MLP: sigmoid(relu(x@W1^T+b1)@W2^T+b2). Block=64 per edge.
// ---------------------------------------------------------------------------
__global__ __launch_bounds__(64) void edge_conf_kernel(const float* __restrict__ edge_x,
                                                       const float* __restrict__ W1,
                                                       const float* __restrict__ b1,
                                                       const float* __restrict__ W2,
                                                       const float* __restrict__ b2,
                                                       float* __restrict__ out_conf) {
    int e = blockIdx.x, j = threadIdx.x;
    const float* x = edge_x + e * EDGE_DIM_;
    float acc = b1[j];
    for (int i = 0; i < EDGE_DIM_; ++i) acc += x[i] * W1[j * EDGE_DIM_ + i];
    float h = fmaxf(acc, 0.f) * W2[j];
    #pragma unroll
    for (int off = 32; off; off >>= 1) h += __shfl_down(h, off);
    if (j == 0) out_conf[e] = 1.f / (1.f + __expf(-(h + b2[0])));
}

// ---------------------------------------------------------------------------
// K4: scatter-mean of edge_x rows onto corners. Block per corner, thread per ch.
// ---------------------------------------------------------------------------
__global__ __launch_bounds__(256) void corner_kernel(const float* __restrict__ edge_x,
                                                     const int* __restrict__ pairs,
                                                     float* __restrict__ corner_features) {
    __shared__ int sp[NP_ * 2];
    int corner = blockIdx.x;
    for (int i = threadIdx.x; i < NP_ * 2; i += 256) sp[i] = pairs[i];
    __syncthreads();
    int c = threadIdx.x;
    float sum = 0.f, cnt = 0.f;
    for (int p = 0; p < NP_; ++p) {
        if (sp[p * 2] == corner) { sum += edge_x[sp[p * 2 + 1] * EDGE_DIM_ + c]; cnt += 1.f; }
    }
    corner_features[corner * EDGE_DIM_ + c] = sum / fmaxf(cnt, 1.f);
}

// ---------------------------------------------------------------------------
// K5: LoopEncoder (3x reflect-pad conv1d k=3 + relu, max over L) + loop conf MLP.
// Block per loop, 64 threads (one per out-channel).
// ---------------------------------------------------------------------------
__global__ __launch_bounds__(64) void loop_enc_kernel(
        const float* __restrict__ corner_features, const float* __restrict__ corners,
        const int* __restrict__ loops,
        const float* __restrict__ Wc0, const float* __restrict__ bc0,
        const float* __restrict__ Wc1, const float* __restrict__ bc1,
        const float* __restrict__ Wc2, const float* __restrict__ bc2,
        const float* __restrict__ Wl1, const float* __restrict__ bl1,
        const float* __restrict__ Wl2, const float* __restrict__ bl2,
        float* __restrict__ loop_features, float* __restrict__ out_loop_conf) {
    __shared__ float inp[LOOP_IN_][LL_];
    __shared__ float ha[64][LL_];
    __shared__ float hb[64][LL_];
    __shared__ float lf[64];
    __shared__ int cidx[LL_];

    int l = blockIdx.x, tid = threadIdx.x;
    if (tid < LL_) cidx[tid] = loops[l * LL_ + tid];
    __syncthreads();
    for (int idx = tid; idx < LOOP_IN_ * LL_; idx += 64) {
        int i = idx / LL_, j = idx % LL_;
        float v = (i < EDGE_DIM_) ? corner_features[cidx[j] * EDGE_DIM_ + i]
                                  : corners[cidx[j] * 2 + (i - EDGE_DIM_)];
        inp[i][j] = v;
    }
    __syncthreads();

    // reflection index maps for k=3, pad 1 (ReflectionPad1d)
    const int rm1[8] = {1, 0, 1, 2, 3, 4, 5, 6};
    const int rp1[8] = {1, 2, 3, 4, 5, 6, 7, 6};
    int o = tid;

    // conv0: 258 -> 64
    {
        float acc[LL_];
        float b = bc0[o];
        #pragma unroll
        for (int t = 0; t < LL_; ++t) acc[t] = b;
        for (int i = 0; i < LOOP_IN_; ++i) {
            float w0 = Wc0[(o * LOOP_IN_ + i) * 3 + 0];
            float w1 = Wc0[(o * LOOP_IN_ + i) * 3 + 1];
            float w2 = Wc0[(o * LOOP_IN_ + i) * 3 + 2];
            #pragma unroll
            for (int t = 0; t < LL_; ++t)
                acc[t] += w0 * inp[i][rm1[t]] + w1 * inp[i][t] + w2 * inp[i][rp1[t]];
        }
        #pragma unroll
        for (int t = 0; t < LL_; ++t) ha[o][t] = fmaxf(acc[t], 0.f);
    }
    __syncthreads();

    // conv1: 64 -> 64
    {
        float acc[LL_];
        float b = bc1[o];
        #pragma unroll
        for (int t = 0; t < LL_; ++t) acc[t] = b;
        for (int i = 0; i < 64; ++i) {
            float w0 = Wc1[(o * 64 + i) * 3 + 0];
            float w1 = Wc1[(o * 64 + i) * 3 + 1];
            float w2 = Wc1[(o * 64 + i) * 3 + 2];
            #pragma unroll
            for (int t = 0; t < LL_; ++t)
                acc[t] += w0 * ha[i][rm1[t]] + w1 * ha[i][t] + w2 * ha[i][rp1[t]];
        }
        #pragma unroll
        for (int t = 0; t < LL_; ++t) hb[o][t] = fmaxf(acc[t], 0.f);
    }
    __syncthreads();

    // conv2: 64 -> 64, then max over L
    {
        float acc[LL_];
        float b = bc2[o];
        #pragma unroll
        for (int t = 0; t < LL_; ++t) acc[t] = b;
        for (int i = 0; i < 64; ++i) {
            float w0 = Wc2[(o * 64 + i) * 3 + 0];
            float w1 = Wc2[(o * 64 + i) * 3 + 1];
            float w2 = Wc2[(o * 64 + i) * 3 + 2];
            #pragma unroll
            for (int t = 0; t < LL_; ++t)
                acc[t] += w0 * hb[i][rm1[t]] + w1 * hb[i][t] + w2 * hb[i][rp1[t]];
        }
        float m = -INFINITY;
        #pragma unroll
        for (int t = 0; t < LL_; ++t) m = fmaxf(m, fmaxf(acc[t], 0.f));
        lf[o] = m;
        loop_features[l * FEAT_ + o] = m;
    }
    __syncthreads();

    // loop confidence MLP (32 hidden)
    float part = 0.f;
    if (tid < 32) {
        float a = bl1[tid];
        for (int o2 = 0; o2 < 64; ++o2) a += lf[o2] * Wl1[tid * 64 + o2];
        part = fmaxf(a, 0.f) * Wl2[tid];
    }
    #pragma unroll
    for (int off = 32; off; off >>= 1) part += __shfl_down(part, off);
    if (tid == 0) out_loop_conf[l] = 1.f / (1.f + __expf(-(part + bl2[0])));
}

// ---------------------------------------------------------------------------
// K6: loop-edge incidence. Block per loop, thread per edge. Writes output directly.
// ---------------------------------------------------------------------------
__global__ __launch_bounds__(256) void loop_edges_kernel(const int* __restrict__ loops,
                                                         const int* __restrict__ edge_corner,
                                                         float* __restrict__ out_le) {
    __shared__ int lp[LL_];
    int l = blockIdx.x;
    if (threadIdx.x < LL_) lp[threadIdx.x] = loops[l * LL_ + threadIdx.x];
    __syncthreads();
    int e = threadIdx.x;
    int a = edge_corner[e * 2], b = edge_corner[e * 2 + 1];
    bool hit = false;
    #pragma unroll
    for (int j = 0; j < LL_; ++j) {
        int x = lp[j], pv = lp[(j + LL_ - 1) & 7], nx = lp[(j + 1) & 7];
        hit = hit || (a == x && (b == pv || b == nx));
    }
    out_le[l * E_ + e] = hit ? 1.f : 0.f;
}

// ---------------------------------------------------------------------------
// K7: confidence-weighted loop-feature average per edge + final 1x1 conv + relu.
// Block per edge, 128 threads. Reads loop_conf / loop_edges from the output buf.
// ---------------------------------------------------------------------------
__global__ __launch_bounds__(128) void final_kernel(const float* __restrict__ coord_x,
                                                    const float* __restrict__ loop_features,
                                                    const float* __restrict__ loop_conf,
                                                    const float* __restrict__ loop_edges,
                                                    const float* __restrict__ W_agg,
                                                    float* __restrict__ out) {
    __shared__ float cf[FEAT_];
    int e = blockIdx.x, tid = threadIdx.x;
    if (tid < FEAT_) {
        float num = 0.f, den = 0.f;
        for (int l = 0; l < NL_; ++l) {
            float w = loop_conf[l] * loop_edges[l * E_ + e];
            den += w;
            num += w * loop_features[l * FEAT_ + tid];
        }
        cf[tid] = num / fmaxf(den, 1e-4f);
    }
    __syncthreads();
    int c = tid;
    const float* wr = W_agg + c * (C_ + FEAT_);
    float acc = 0.f;
    for (int j = 0; j < C_; ++j) acc += coord_x[e * C_ + j] * wr[j];
    for (int f = 0; f < FEAT_; ++f) acc += cf[f] * wr[C_ + f];
    out[e * C_ + c] = fmaxf(acc, 0.f);
}

// ---------------------------------------------------------------------------
extern "C" void kernel_launch(void* const* d_in, const int* in_sizes, int n_in,
                              void* d_out, int out_size, void* d_ws, size_t ws_size,
                              hipStream_t stream) {
    const float* image_x     = (const float*)d_in[0];
    const float* coord_x     = (const float*)d_in[1];
    const float* corners     = (const float*)d_in[2];
    const int*   cep         = (const int*)d_in[3];
    const int*   edge_corner = (const int*)d_in[4];
    const int*   loops       = (const int*)d_in[5];
    const float* W_ep1 = (const float*)d_in[6];
    const float* b_ep1 = (const float*)d_in[7];
    const float* W_ep2 = (const float*)d_in[8];
    const float* b_ep2 = (const float*)d_in[9];
    const float* Wc0   = (const float*)d_in[10];
    const float* bc0   = (const float*)d_in[11];
    const float* Wc1   = (const float*)d_in[12];
    const float* bc1   = (const float*)d_in[13];
    const float* Wc2   = (const float*)d_in[14];
    const float* bc2   = (const float*)d_in[15];
    const float* Wl1   = (const float*)d_in[16];
    const float* bl1   = (const float*)d_in[17];
    const float* Wl2   = (const float*)d_in[18];
    const float* bl2   = (const float*)d_in[19];
    const float* W_agg = (const float*)d_in[20];

    float* out       = (float*)d_out;
    float* out_main  = out;                       // [E, C]    = 32768
    float* out_econf = out + E_ * C_;             // [E]       = 256
    float* out_lconf = out_econf + E_;            // [NL]      = 64
    float* out_le    = out_lconf + NL_;           // [NL, E]   = 16384

    float* edge_x          = (float*)d_ws;                       // E * 256
    float* corner_features = edge_x + E_ * EDGE_DIM_;            // NC * 256
    float* loop_features   = corner_features + NC_ * EDGE_DIM_;  // NL * 64

    pool_kernel<<<dim3(E_ * C_ / 4), dim3(256), 0, stream>>>(image_x, edge_x);
    coord_copy_kernel<<<dim3(E_ * C_ / 256), dim3(256), 0, stream>>>(coord_x, edge_x);
    edge_conf_kernel<<<dim3(E_), dim3(64), 0, stream>>>(edge_x, W_ep1, b_ep1, W_ep2, b_ep2, out_econf);
    corner_kernel<<<dim3(NC_), dim3(256), 0, stream>>>(edge_x, cep, corner_features);
    loop_enc_kernel<<<dim3(NL_), dim3(64), 0, stream>>>(corner_features, corners, loops,
                                                        Wc0, bc0, Wc1, bc1, Wc2, bc2,
                                                        Wl1, bl1, Wl2, bl2,
                                                        loop_features, out_lconf);
    loop_edges_kernel<<<dim3(NL_), dim3(256), 0, stream>>>(loops, edge_corner, out_le);
    final_kernel<<<dim3(E_), dim3(128), 0, stream>>>(coord_x, loop_features, out_lconf,
                                                     out_le, W_agg, out_main);
}

// Round 4
// 638.862 us; speedup vs baseline: 1.0736x; 1.0736x over previous
//
#include <hip/hip_runtime.h>
#include <math.h>

// Problem constants (fixed shapes from reference)
#define E_      256
#define C_      128
#define S_      3136   // 56*56
#define NC_     200
#define NP_     512
#define NL_     64
#define LL_     8
#define EDGE_DIM_ 256  // 2*C
#define LOOP_IN_  258  // EDGE_DIM + 2
#define FEAT_   64

// ---------------------------------------------------------------------------
// K1: global max-pool over H*W per (e,c) row + coord copy. One wave per row.
// Row = 3136 f32 = 784 float4 chunks = 12 full wave iterations + 16 tail.
// ---------------------------------------------------------------------------
__global__ __launch_bounds__(256) void pool_kernel(const float* __restrict__ image_x,
                                                   const float* __restrict__ coord_x,
                                                   float* __restrict__ edge_x) {
    int row  = blockIdx.x * 4 + (threadIdx.x >> 6);   // (e*C + c)
    int lane = threadIdx.x & 63;
    const float4* p = reinterpret_cast<const float4*>(image_x) + (size_t)row * (S_ / 4);

    float m = -INFINITY;
    #pragma unroll
    for (int it = 0; it < 12; ++it) {
        float4 v = p[lane + it * 64];
        m = fmaxf(m, fmaxf(fmaxf(v.x, v.y), fmaxf(v.z, v.w)));
    }
    if (lane < 16) {   // tail chunks 768..783
        float4 v = p[768 + lane];
        m = fmaxf(m, fmaxf(fmaxf(v.x, v.y), fmaxf(v.z, v.w)));
    }
    #pragma unroll
    for (int off = 32; off; off >>= 1) m = fmaxf(m, __shfl_down(m, off));
    if (lane == 0) {
        int e = row >> 7, c = row & 127;
        edge_x[e * EDGE_DIM_ + c] = m;
        edge_x[e * EDGE_DIM_ + C_ + c] = coord_x[row];   // fused coord copy
    }
}

// ---------------------------------------------------------------------------
// K2 (mid): block-range dispatch of three independent jobs:
//   blocks [0,64):    edge confidence MLP, 4 edges/block (one wave each),
//                     x rows staged in LDS, W1 rows streamed from global (L2)
//   blocks [64,264):  corner scatter-mean, one corner/block
//   blocks [264,328): loop-edge incidence, one loop/block
// ---------------------------------------------------------------------------
#define MID_A_  64
#define MID_B_  (MID_A_ + NC_)     // 264
#define MID_N_  (MID_B_ + NL_)     // 328

__global__ __launch_bounds__(256) void mid_kernel(const float* __restrict__ edge_x,
                                                  const float* __restrict__ W1,
                                                  const float* __restrict__ b1,
                                                  const float* __restrict__ W2,
                                                  const float* __restrict__ b2,
                                                  const int* __restrict__ pairs,
                                                  const int* __restrict__ loops,
                                                  const int* __restrict__ edge_corner,
                                                  float* __restrict__ out_econf,
                                                  float* __restrict__ corner_features,
                                                  float* __restrict__ out_le) {
    __shared__ float smem[4 * EDGE_DIM_];   // 1024 floats; reused as int[1024]
    int b = blockIdx.x, tid = threadIdx.x;

    if (b < MID_A_) {
        // ---- edge confidence: edges 4b..4b+3, one wave per edge ----
        float* xs = smem;                  // [4][256]
        for (int idx = tid; idx < 4 * EDGE_DIM_; idx += 256)
            xs[idx] = edge_x[b * 4 * EDGE_DIM_ + idx];
        __syncthreads();
        int w = tid >> 6, j = tid & 63;
        int e = b * 4 + w;
        const float* x = xs + w * EDGE_DIM_;
        const float* wr = W1 + j * EDGE_DIM_;
        float acc = b1[j];
        #pragma unroll 8
        for (int i = 0; i < EDGE_DIM_; ++i) acc += x[i] * wr[i];
        float h = fmaxf(acc, 0.f) * W2[j];
        #pragma unroll
        for (int off = 32; off; off >>= 1) h += __shfl_down(h, off);
        if (j == 0) out_econf[e] = 1.f / (1.f + __expf(-(h + b2[0])));
    } else if (b < MID_B_) {
        // ---- corner scatter-mean ----
        int* sp = reinterpret_cast<int*>(smem);
        int corner = b - MID_A_;
        for (int i = tid; i < NP_ * 2; i += 256) sp[i] = pairs[i];
        __syncthreads();
        int c = tid;
        float sum = 0.f, cnt = 0.f;
        for (int p = 0; p < NP_; ++p) {
            if (sp[p * 2] == corner) { sum += edge_x[sp[p * 2 + 1] * EDGE_DIM_ + c]; cnt += 1.f; }
        }
        corner_features[corner * EDGE_DIM_ + c] = sum / fmaxf(cnt, 1.f);
    } else {
        // ---- loop-edge incidence ----
        int* lp = reinterpret_cast<int*>(smem);
        int l = b - MID_B_;
        if (tid < LL_) lp[tid] = loops[l * LL_ + tid];
        __syncthreads();
        int e = tid;
        int a = edge_corner[e * 2], bb = edge_corner[e * 2 + 1];
        bool hit = false;
        #pragma unroll
        for (int j = 0; j < LL_; ++j) {
            int x = lp[j], pv = lp[(j + LL_ - 1) & 7], nx = lp[(j + 1) & 7];
            hit = hit || (a == x && (bb == pv || bb == nx));
        }
        out_le[l * E_ + e] = hit ? 1.f : 0.f;
    }
}

// ---------------------------------------------------------------------------
// K3: LoopEncoder (3x reflect-pad conv1d k=3 + relu, max over L) + loop conf.
// Block per loop, 256 threads: (o = tid&63, s = tid>>6) — 4-way split of the
// input-channel loop; padded-LDS partial reduction (stride 9 -> conflict-free).
// ---------------------------------------------------------------------------
__global__ __launch_bounds__(256) void loop_enc_kernel(
        const float* __restrict__ corner_features, const float* __restrict__ corners,
        const int* __restrict__ loops,
        const float* __restrict__ Wc0, const float* __restrict__ bc0,
        const float* __restrict__ Wc1, const float* __restrict__ bc1,
        const float* __restrict__ Wc2, const float* __restrict__ bc2,
        const float* __restrict__ Wl1, const float* __restrict__ bl1,
        const float* __restrict__ Wl2, const float* __restrict__ bl2,
        float* __restrict__ loop_features, float* __restrict__ out_loop_conf) {
    __shared__ float inp[LOOP_IN_ * LL_];   // [258][8]
    __shared__ float part[4 * 64 * 9];      // [s][o][t] padded
    __shared__ float ha[64 * 9];            // [o][t] padded
    __shared__ float hb[64 * 9];
    __shared__ float lf[64];
    __shared__ int cidx[LL_];

    int l = blockIdx.x, tid = threadIdx.x;
    int o = tid & 63, s = tid >> 6;
    if (tid < LL_) cidx[tid] = loops[l * LL_ + tid];
    __syncthreads();
    for (int idx = tid; idx < LOOP_IN_ * LL_; idx += 256) {
        int i = idx >> 3, j = idx & 7;
        inp[idx] = (i < EDGE_DIM_) ? corner_features[cidx[j] * EDGE_DIM_ + i]
                                   : corners[cidx[j] * 2 + (i - EDGE_DIM_)];
    }
    __syncthreads();

    // reflection index maps for k=3, pad 1 (ReflectionPad1d)
    const int rm1[8] = {1, 0, 1, 2, 3, 4, 5, 6};
    const int rp1[8] = {1, 2, 3, 4, 5, 6, 7, 6};

    // ---- conv0: 258 -> 64, i-range split 65/65/64/64 ----
    {
        float acc[LL_];
        #pragma unroll
        for (int t = 0; t < LL_; ++t) acc[t] = 0.f;
        int lo = s * 64 + (s < 2 ? s : 2);
        int hi = lo + (s < 2 ? 65 : 64);
        for (int i = lo; i < hi; ++i) {
            float w0 = Wc0[(o * LOOP_IN_ + i) * 3 + 0];
            float w1 = Wc0[(o * LOOP_IN_ + i) * 3 + 1];
            float w2 = Wc0[(o * LOOP_IN_ + i) * 3 + 2];
            const float* ip = inp + i * LL_;
            #pragma unroll
            for (int t = 0; t < LL_; ++t)
                acc[t] += w0 * ip[rm1[t]] + w1 * ip[t] + w2 * ip[rp1[t]];
        }
        #pragma unroll
        for (int t = 0; t < LL_; ++t) part[(s * 64 + o) * 9 + t] = acc[t];
    }
    __syncthreads();
    if (tid < 64) {
        #pragma unroll
        for (int t = 0; t < LL_; ++t) {
            float v = bc0[tid];
            #pragma unroll
            for (int ss = 0; ss < 4; ++ss) v += part[(ss * 64 + tid) * 9 + t];
            ha[tid * 9 + t] = fmaxf(v, 0.f);
        }
    }
    __syncthreads();

    // ---- conv1: 64 -> 64, i-range split 16 each ----
    {
        float acc[LL_];
        #pragma unroll
        for (int t = 0; t < LL_; ++t) acc[t] = 0.f;
        for (int i = s * 16; i < s * 16 + 16; ++i) {
            float w0 = Wc1[(o * 64 + i) * 3 + 0];
            float w1 = Wc1[(o * 64 + i) * 3 + 1];
            float w2 = Wc1[(o * 64 + i) * 3 + 2];
            const float* ip = ha + i * 9;
            #pragma unroll
            for (int t = 0; t < LL_; ++t)
                acc[t] += w0 * ip[rm1[t]] + w1 * ip[t] + w2 * ip[rp1[t]];
        }
        #pragma unroll
        for (int t = 0; t < LL_; ++t) part[(s * 64 + o) * 9 + t] = acc[t];
    }
    __syncthreads();
    if (tid < 64) {
        #pragma unroll
        for (int t = 0; t < LL_; ++t) {
            float v = bc1[tid];
            #pragma unroll
            for (int ss = 0; ss < 4; ++ss) v += part[(ss * 64 + tid) * 9 + t];
            hb[tid * 9 + t] = fmaxf(v, 0.f);
        }
    }
    __syncthreads();

    // ---- conv2: 64 -> 64, then relu + max over L ----
    {
        float acc[LL_];
        #pragma unroll
        for (int t = 0; t < LL_; ++t) acc[t] = 0.f;
        for (int i = s * 16; i < s * 16 + 16; ++i) {
            float w0 = Wc2[(o * 64 + i) * 3 + 0];
            float w1 = Wc2[(o * 64 + i) * 3 + 1];
            float w2 = Wc2[(o * 64 + i) * 3 + 2];
            const float* ip = hb + i * 9;
            #pragma unroll
            for (int t = 0; t < LL_; ++t)
                acc[t] += w0 * ip[rm1[t]] + w1 * ip[t] + w2 * ip[rp1[t]];
        }
        #pragma unroll
        for (int t = 0; t < LL_; ++t) part[(s * 64 + o) * 9 + t] = acc[t];
    }
    __syncthreads();
    if (tid < 64) {
        float m = -INFINITY;
        #pragma unroll
        for (int t = 0; t < LL_; ++t) {
            float v = bc2[tid];
            #pragma unroll
            for (int ss = 0; ss < 4; ++ss) v += part[(ss * 64 + tid) * 9 + t];
            m = fmaxf(m, fmaxf(v, 0.f));
        }
        lf[tid] = m;
        loop_features[l * FEAT_ + tid] = m;
    }
    __syncthreads();

    // ---- loop confidence MLP (32 hidden), wave 0 only ----
    float pv = 0.f;
    if (tid < 32) {
        float a = bl1[tid];
        for (int o2 = 0; o2 < 64; ++o2) a += lf[o2] * Wl1[tid * 64 + o2];
        pv = fmaxf(a, 0.f) * Wl2[tid];
    }
    #pragma unroll
    for (int off = 32; off; off >>= 1) pv += __shfl_down(pv, off);
    if (tid == 0) out_loop_conf[l] = 1.f / (1.f + __expf(-(pv + bl2[0])));
}

// ---------------------------------------------------------------------------
// K4: confidence-weighted loop-feature average per edge + final 1x1 conv + relu.
// Block per edge, 128 threads. Reads loop_conf / loop_edges from the output buf.
// ---------------------------------------------------------------------------
__global__ __launch_bounds__(128) void final_kernel(const float* __restrict__ coord_x,
                                                    const float* __restrict__ loop_features,
                                                    const float* __restrict__ loop_conf,
                                                    const float* __restrict__ loop_edges,
                                                    const float* __restrict__ W_agg,
                                                    float* __restrict__ out) {
    __shared__ float cf[FEAT_];
    int e = blockIdx.x, tid = threadIdx.x;
    if (tid < FEAT_) {
        float num = 0.f, den = 0.f;
        for (int l = 0; l < NL_; ++l) {
            float w = loop_conf[l] * loop_edges[l * E_ + e];
            den += w;
            num += w * loop_features[l * FEAT_ + tid];
        }
        cf[tid] = num / fmaxf(den, 1e-4f);
    }
    __syncthreads();
    int c = tid;
    const float* wr = W_agg + c * (C_ + FEAT_);
    float acc = 0.f;
    for (int j = 0; j < C_; ++j) acc += coord_x[e * C_ + j] * wr[j];
    for (int f = 0; f < FEAT_; ++f) acc += cf[f] * wr[C_ + f];
    out[e * C_ + c] = fmaxf(acc, 0.f);
}

// ---------------------------------------------------------------------------
extern "C" void kernel_launch(void* const* d_in, const int* in_sizes, int n_in,
                              void* d_out, int out_size, void* d_ws, size_t ws_size,
                              hipStream_t stream) {
    const float* image_x     = (const float*)d_in[0];
    const float* coord_x     = (const float*)d_in[1];
    const float* corners     = (const float*)d_in[2];
    const int*   cep         = (const int*)d_in[3];
    const int*   edge_corner = (const int*)d_in[4];
    const int*   loops       = (const int*)d_in[5];
    const float* W_ep1 = (const float*)d_in[6];
    const float* b_ep1 = (const float*)d_in[7];
    const float* W_ep2 = (const float*)d_in[8];
    const float* b_ep2 = (const float*)d_in[9];
    const float* Wc0   = (const float*)d_in[10];
    const float* bc0   = (const float*)d_in[11];
    const float* Wc1   = (const float*)d_in[12];
    const float* bc1   = (const float*)d_in[13];
    const float* Wc2   = (const float*)d_in[14];
    const float* bc2   = (const float*)d_in[15];
    const float* Wl1   = (const float*)d_in[16];
    const float* bl1   = (const float*)d_in[17];
    const float* Wl2   = (const float*)d_in[18];
    const float* bl2   = (const float*)d_in[19];
    const float* W_agg = (const float*)d_in[20];

    float* out       = (float*)d_out;
    float* out_main  = out;                       // [E, C]    = 32768
    float* out_econf = out + E_ * C_;             // [E]       = 256
    float* out_lconf = out_econf + E_;            // [NL]      = 64
    float* out_le    = out_lconf + NL_;           // [NL, E]   = 16384

    float* edge_x          = (float*)d_ws;                       // E * 256
    float* corner_features = edge_x + E_ * EDGE_DIM_;            // NC * 256
    float* loop_features   = corner_features + NC_ * EDGE_DIM_;  // NL * 64

    pool_kernel<<<dim3(E_ * C_ / 4), dim3(256), 0, stream>>>(image_x, coord_x, edge_x);
    mid_kernel<<<dim3(MID_N_), dim3(256), 0, stream>>>(edge_x, W_ep1, b_ep1, W_ep2, b_ep2,
                                                       cep, loops, edge_corner,
                                                       out_econf, corner_features, out_le);
    loop_enc_kernel<<<dim3(NL_), dim3(256), 0, stream>>>(corner_features, corners, loops,
                                                         Wc0, bc0, Wc1, bc1, Wc2, bc2,
                                                         Wl1, bl1, Wl2, bl2,
                                                         loop_features, out_lconf);
    final_kernel<<<dim3(E_), dim3(128), 0, stream>>>(coord_x, loop_features, out_lconf,
                                                     out_le, W_agg, out_main);
}